// Round 4
// baseline (493.716 us; speedup 1.0000x reference)
//
#include <hip/hip_runtime.h>
#include <hip/hip_bf16.h>
#include <cstdint>

// B=8, C=256, N=4096 spatial self-attention.
// R8: (1) attn restructured: 256 blocks x 256 thr (4 waves x 32 queries), NO
// in-block key-split -- each wave walks all 4096 keys in 128 iters of KT=32.
// LDS halves to ~64 KB -> 2 independent blocks/CU (phase-decoupled barriers;
// one block's softmax/staging overlaps the other's MFMA). Merge epilogue
// deleted entirely. (2) V-read bank fix: read slot = (quad + (c>>1))&3
// rotation with matching global-source pre-rotation (LDS dst stays linear for
// global_load_lds); each 8-lane issue group now covers all 8 bank-quads.
// Keeps: swapped QK^T w/ lane-local P, DPP wave-max, defer-rescale THR=8,
// Q/V pair-interleave, XOR-swizzled K staging, 3-pass qkv.

typedef short short8 __attribute__((ext_vector_type(8)));
typedef short short4v __attribute__((ext_vector_type(4)));
typedef float f32x4 __attribute__((ext_vector_type(4)));
typedef unsigned int uint4v __attribute__((ext_vector_type(4)));

#define MFMA16(a, b, c) __builtin_amdgcn_mfma_f32_16x16x32_bf16((a), (b), (c), 0, 0, 0)
#define LOG2E 1.4426950408889634f

__device__ __forceinline__ unsigned short f2bf(float f) {
    union { float f; unsigned int u; } v;
    v.f = f;
    unsigned int u = v.u;
    return (unsigned short)((u + 0x7fffu + ((u >> 16) & 1u)) >> 16);
}

__device__ __forceinline__ void load_lds16(const unsigned short* g, unsigned short* l) {
    __builtin_amdgcn_global_load_lds(
        (const __attribute__((address_space(1))) unsigned int*)g,
        (__attribute__((address_space(3))) unsigned int*)l, 16, 0, 0);
}

// max over the 16-lane row group via DPP row_ror (VALU only, no LDS unit)
__device__ __forceinline__ float rowmax16_dpp(float x) {
    int v;
    v = __builtin_amdgcn_update_dpp(0, __float_as_int(x), 0x121, 0xf, 0xf, false);
    x = fmaxf(x, __int_as_float(v));
    v = __builtin_amdgcn_update_dpp(0, __float_as_int(x), 0x122, 0xf, 0xf, false);
    x = fmaxf(x, __int_as_float(v));
    v = __builtin_amdgcn_update_dpp(0, __float_as_int(x), 0x124, 0xf, 0xf, false);
    x = fmaxf(x, __int_as_float(v));
    v = __builtin_amdgcn_update_dpp(0, __float_as_int(x), 0x128, 0xf, 0xf, false);
    x = fmaxf(x, __int_as_float(v));
    return x;
}

// 16-group maxes -> full-wave max broadcast, VALU-only (row_bcast15/31 + readlane)
__device__ __forceinline__ float wavemax_bcast(float x) {
    int v;
    v = __builtin_amdgcn_update_dpp(__float_as_int(x), __float_as_int(x), 0x142, 0xf, 0xf, false);
    x = fmaxf(x, __int_as_float(v));
    v = __builtin_amdgcn_update_dpp(__float_as_int(x), __float_as_int(x), 0x143, 0xf, 0xf, false);
    x = fmaxf(x, __int_as_float(v));
    return __int_as_float(__builtin_amdgcn_readlane(__float_as_int(x), 63));
}

// ---------------- Kernel 0: weight fp32 -> bf16 ------------------------------
__global__ __launch_bounds__(256) void wcvt_kernel(
    const float* __restrict__ wq, const float* __restrict__ wk,
    const float* __restrict__ wv, unsigned short* __restrict__ Wb)
{
    int idx = (blockIdx.x * 256 + threadIdx.x) * 4;
    const float* src = (idx < 65536) ? wq : ((idx < 131072) ? wk : wv);
    float4 f = *(const float4*)(src + (idx & 65535));
    short4v s = { (short)f2bf(f.x), (short)f2bf(f.y), (short)f2bf(f.z), (short)f2bf(f.w) };
    *(short4v*)(Wb + idx) = s;
}

// ---------------- Kernel 1: QKV projection via MFMA --------------------------
// 1024 blocks x 256 thr (4 waves). Block: batch b, 32 tokens; wave: 64 channels.
// Three sequential passes (Q, V, K). Qc AND Vc both [B][C][N] bf16,
// pair-interleaved per 32-token chunk: u32 slot a <- tokens (a, a+16).
// Q pre-scaled by log2e. Kr [B][N][C].
__global__ __launch_bounds__(256, 2) void qkv_kernel(
    const float* __restrict__ x, const unsigned short* __restrict__ Wb,
    const float* __restrict__ bq, const float* __restrict__ bk,
    const float* __restrict__ bv,
    unsigned short* __restrict__ Qc, unsigned short* __restrict__ Kr,
    unsigned short* __restrict__ Vc)
{
    const int C = 256, N = 4096;
    __shared__ __align__(16) unsigned short Xt[32][264];   // [token][c], pad 264

    const int tid  = threadIdx.x;
    const int bid  = blockIdx.x;
    const int b    = bid >> 7;
    const int n0   = (bid & 127) * 32;
    const int wave = tid >> 6;
    const int lane = tid & 63;
    const int quad = lane >> 4;
    const int l16  = lane & 15;
    const int ch0  = wave * 64;

    // stage X^T tile: fp32 [c][token] -> bf16 LDS [token][c]
    {
        const int token = tid & 31;
        const int cg    = tid >> 5;
        const float* xb = x + ((size_t)b * C) * N + n0 + token;
#pragma unroll
        for (int p = 0; p < 8; p++) {
            int c0 = p * 32 + cg * 4;
            float f0 = xb[(size_t)(c0 + 0) * N];
            float f1 = xb[(size_t)(c0 + 1) * N];
            float f2 = xb[(size_t)(c0 + 2) * N];
            float f3 = xb[(size_t)(c0 + 3) * N];
            short4v s = { (short)f2bf(f0), (short)f2bf(f1), (short)f2bf(f2), (short)f2bf(f3) };
            *(short4v*)(&Xt[token][c0]) = s;
        }
    }
    __syncthreads();

    f32x4 acc[4][2];

    // ---------------- pass 0: Q (m=0), scaled by log2e, pair-interleaved -----
#pragma unroll
    for (int ct = 0; ct < 4; ct++)
#pragma unroll
        for (int tt = 0; tt < 2; tt++) acc[ct][tt] = (f32x4){0.f, 0.f, 0.f, 0.f};
#pragma unroll
    for (int kc = 0; kc < 8; kc++) {
        const int ko = kc * 32 + quad * 8;
        short8 ax0 = *(const short8*)(&Xt[l16][ko]);
        short8 ax1 = *(const short8*)(&Xt[16 + l16][ko]);
#pragma unroll
        for (int ct = 0; ct < 4; ct++) {
            short8 wf = *(const short8*)(Wb + (ch0 + ct * 16 + l16) * 256 + ko);
            acc[ct][0] = MFMA16(ax0, wf, acc[ct][0]);
            acc[ct][1] = MFMA16(ax1, wf, acc[ct][1]);
        }
    }
#pragma unroll
    for (int ct = 0; ct < 4; ct++) {
        const int ch = ch0 + ct * 16 + l16;
        const float biq = bq[ch];
        uint4v qv;
#pragma unroll
        for (int r = 0; r < 4; r++) {
            unsigned int lo = f2bf((acc[ct][0][r] + biq) * LOG2E);   // token quad*4+r
            unsigned int hi = f2bf((acc[ct][1][r] + biq) * LOG2E);   // token quad*4+r+16
            qv[r] = lo | (hi << 16);
        }
        *(uint4v*)(Qc + ((size_t)b * C + ch) * N + n0 + quad * 8) = qv;
    }

    // ---------------- pass 1: V (m=2), pair-interleaved b128 stores ----------
#pragma unroll
    for (int ct = 0; ct < 4; ct++)
#pragma unroll
        for (int tt = 0; tt < 2; tt++) acc[ct][tt] = (f32x4){0.f, 0.f, 0.f, 0.f};
#pragma unroll
    for (int kc = 0; kc < 8; kc++) {
        const int ko = kc * 32 + quad * 8;
        short8 ax0 = *(const short8*)(&Xt[l16][ko]);
        short8 ax1 = *(const short8*)(&Xt[16 + l16][ko]);
#pragma unroll
        for (int ct = 0; ct < 4; ct++) {
            short8 wf = *(const short8*)(Wb + (2 << 16) + (ch0 + ct * 16 + l16) * 256 + ko);
            acc[ct][0] = MFMA16(ax0, wf, acc[ct][0]);
            acc[ct][1] = MFMA16(ax1, wf, acc[ct][1]);
        }
    }
#pragma unroll
    for (int ct = 0; ct < 4; ct++) {
        const int ch = ch0 + ct * 16 + l16;
        const float biv = bv[ch];
        uint4v vv;
#pragma unroll
        for (int r = 0; r < 4; r++) {
            unsigned int lo = f2bf(acc[ct][0][r] + biv);
            unsigned int hi = f2bf(acc[ct][1][r] + biv);
            vv[r] = lo | (hi << 16);
        }
        *(uint4v*)(Vc + ((size_t)b * C + ch) * N + n0 + quad * 8) = vv;
    }

    // ---------------- pass 2: K (m=1), transpose via LDS ----------------
#pragma unroll
    for (int ct = 0; ct < 4; ct++)
#pragma unroll
        for (int tt = 0; tt < 2; tt++) acc[ct][tt] = (f32x4){0.f, 0.f, 0.f, 0.f};
#pragma unroll
    for (int kc = 0; kc < 8; kc++) {
        const int ko = kc * 32 + quad * 8;
        short8 ax0 = *(const short8*)(&Xt[l16][ko]);
        short8 ax1 = *(const short8*)(&Xt[16 + l16][ko]);
#pragma unroll
        for (int ct = 0; ct < 4; ct++) {
            short8 wf = *(const short8*)(Wb + (1 << 16) + (ch0 + ct * 16 + l16) * 256 + ko);
            acc[ct][0] = MFMA16(ax0, wf, acc[ct][0]);
            acc[ct][1] = MFMA16(ax1, wf, acc[ct][1]);
        }
    }
    __syncthreads();    // Xt reads all done (all passes)
#pragma unroll
    for (int ct = 0; ct < 4; ct++) {
        const int ch = ch0 + ct * 16 + l16;
        const float bik = bk[ch];
#pragma unroll
        for (int tt = 0; tt < 2; tt++) {
#pragma unroll
            for (int r = 0; r < 4; r++)
                Xt[tt * 16 + quad * 4 + r][ch] = f2bf(acc[ct][tt][r] + bik);
        }
    }
    __syncthreads();
#pragma unroll
    for (int p = 0; p < 2; p++) {
        int chunk = p * 256 + tid;          // 0..511
        int tok = chunk >> 4;
        int cc  = (chunk & 15) * 16;
        *(short8*)(Kr + ((size_t)b * N + n0 + tok) * C + cc) = *(const short8*)(&Xt[tok][cc]);
    }
}

// ---------------- Kernel 2: flash attention + epilogue -----------------------
// 256 blocks x 256 thr (4 waves), 2 blocks/CU. b = bid&7, qtile = bid>>3.
// Wave w: queries q0 = qtile*128 + w*32 (halves L/H of 16), ALL 4096 keys in
// 128 iters of KT=32, double-buffered 32KB tiles. No merge epilogue.
// Swapped QK^T: lane (quad,l16) holds S^T[key=4q+r][q=l16] -> PV A-frag is
// lane-local cvt_pk pairs matching pair-interleaved V.
// V LDS: row c (64B), read slot sigma=(quad+(c>>1))&3 rotation; source
// pre-rotated j=(s-(c>>1))&3 so content at sigma = key-group quad.
__global__ __launch_bounds__(256, 2) void attn_kernel(
    const unsigned short* __restrict__ Qc,
    const unsigned short* __restrict__ Kr,
    const unsigned short* __restrict__ Vc,
    const float* __restrict__ x,
    const float* __restrict__ gamma,
    float* __restrict__ out)
{
    const int C = 256, N = 4096;
    __shared__ __align__(16) unsigned short KV[2][16384];   // 64 KB
    __shared__ float Lw[4][32];                              // per-wave l by query

    const int tid  = threadIdx.x;
    const int wave = tid >> 6;
    const int lane = tid & 63;
    const int quad = lane >> 4;
    const int l16  = lane & 15;
    const int bid  = blockIdx.x;
    const int b    = bid & 7;
    const int q0   = (bid >> 3) * 128 + wave * 32;

    const unsigned short* kb  = Kr + (size_t)b * N * C;
    const unsigned short* vcb = Vc + (size_t)b * C * N;

    // Q fragments (B-operand): one u32 per (ch, pair l16) = tokens (q0+l16, +16)
    short8 aqL[8], aqH[8];
    {
        const unsigned int* qb32 = (const unsigned int*)(Qc + (size_t)b * C * N);
#pragma unroll
        for (int f = 0; f < 8; f++) {
#pragma unroll
            for (int j = 0; j < 8; j++) {
                size_t i32 = ((size_t)(f * 32 + quad * 8 + j) * N + q0) / 2 + l16;
                unsigned int u = qb32[i32];
                aqL[f][j] = (short)(u & 0xffff);
                aqH[f][j] = (short)(u >> 16);
            }
        }
    }

    f32x4 oL[16], oH[16];
#pragma unroll
    for (int t = 0; t < 16; t++) {
        oL[t] = (f32x4){0.f, 0.f, 0.f, 0.f};
        oH[t] = (f32x4){0.f, 0.f, 0.f, 0.f};
    }
    float m_w = -__builtin_inff();
    float l_pL = 0.f, l_pH = 0.f;        // partial l for query l16 (+16 for H)

    // stage one KT=32 K/V tile (block-wide, 256 thr x 8 chunks of 16B)
    auto stage = [&](int buf, int m0) {
        unsigned short* dst = &KV[buf][0];
#pragma unroll
        for (int p = 0; p < 4; p++) {               // K: 1024 chunks
            int idx = p * 256 + tid;
            int key = idx >> 5;
            int j = (idx & 31) ^ (key & 31);
            load_lds16(kb + (size_t)(m0 + key) * C + j * 8, dst + idx * 8);
        }
#pragma unroll
        for (int p = 0; p < 4; p++) {               // V: 1024 chunks
            int idx = p * 256 + tid;
            int c = idx >> 2;
            int s = idx & 3;
            int j = (s - (c >> 1)) & 3;             // source pre-rotation
            load_lds16(vcb + (size_t)c * N + m0 + j * 8, dst + 8192 + idx * 8);
        }
    };

    stage(0, 0);
    __syncthreads();

    const int vsl = ((quad + (l16 >> 1)) & 3) * 8;  // V read slot (lane-const)

    for (int it = 0; it < 128; ++it) {
        const int cur = it & 1;
        if (it < 127) stage(cur ^ 1, (it + 1) * 32);

        const unsigned short* Kb = &KV[cur][0];
        const unsigned short* Vb = Kb + 8192;

        // ---- S^T = K Q^T : rows = keys, cols = queries
        f32x4 tL0 = {0.f,0.f,0.f,0.f}, tL1 = {0.f,0.f,0.f,0.f};
        f32x4 tH0 = {0.f,0.f,0.f,0.f}, tH1 = {0.f,0.f,0.f,0.f};
#pragma unroll
        for (int f = 0; f < 8; f++) {
            const int j = f * 4 + quad;
            int k0 = l16, k1 = 16 + l16;
            short8 kf0 = *(const short8*)(Kb + (k0 * 32 + (j ^ (k0 & 31))) * 8);
            short8 kf1 = *(const short8*)(Kb + (k1 * 32 + (j ^ (k1 & 31))) * 8);
            tL0 = MFMA16(kf0, aqL[f], tL0);
            tL1 = MFMA16(kf1, aqL[f], tL1);
            tH0 = MFMA16(kf0, aqH[f], tH0);
            tH1 = MFMA16(kf1, aqH[f], tH1);
        }

        // ---- wave-wide online max (base-2 logits; VALU-only reduction)
        float mx = fmaxf(fmaxf(fmaxf(tL0[0], tL0[1]), fmaxf(tL0[2], tL0[3])),
                         fmaxf(fmaxf(tL1[0], tL1[1]), fmaxf(tL1[2], tL1[3])));
        mx = fmaxf(mx, fmaxf(fmaxf(fmaxf(tH0[0], tH0[1]), fmaxf(tH0[2], tH0[3])),
                             fmaxf(fmaxf(tH1[0], tH1[1]), fmaxf(tH1[2], tH1[3]))));
        mx = rowmax16_dpp(mx);
        mx = wavemax_bcast(mx);

        // ---- defer-rescale (T13): only pay the rescale when max grows by >8
        if (mx > m_w + 8.0f) {
            const float al = exp2f(m_w - mx);   // 0 on first iter
            m_w = mx;
            l_pL *= al; l_pH *= al;
#pragma unroll
            for (int t = 0; t < 16; t++) { oL[t] *= al; oH[t] *= al; }
        }
        const float mn = m_w;

        // ---- exps -> lane-local PV A-fragments (zero LDS)
        uint4v apLu, apHu;
#pragma unroll
        for (int w = 0; w < 4; w++) {
            float e0 = exp2f(tL0[w] - mn);
            float e1 = exp2f(tL1[w] - mn);
            l_pL += e0 + e1;
            union { __hip_bfloat162 v; unsigned int u; } cv;
            cv.v = __float22bfloat162_rn(float2{e0, e1});
            apLu[w] = cv.u;
            float g0 = exp2f(tH0[w] - mn);
            float g1 = exp2f(tH1[w] - mn);
            l_pH += g0 + g1;
            union { __hip_bfloat162 v; unsigned int u; } cw;
            cw.v = __float22bfloat162_rn(float2{g0, g1});
            apHu[w] = cw.u;
        }
        short8 apL, apH;
        {
            union { uint4v u; short8 s; } c1; c1.u = apLu; apL = c1.s;
            union { uint4v u; short8 s; } c2; c2.u = apHu; apH = c2.s;
        }

        // ---- PV: 16 channel-tiles, each V fragment feeds both halves
#pragma unroll
        for (int t = 0; t < 16; t++) {
            short8 vf = *(const short8*)(Vb + t * 512 + l16 * 32 + vsl);
            oL[t] = MFMA16(apL, vf, oL[t]);
            oH[t] = MFMA16(apH, vf, oH[t]);
        }
        __syncthreads();
    }

    // ---- redistribute l across quads (keys split over the 4 quad-lanes)
    l_pL += __shfl_xor(l_pL, 16);
    l_pL += __shfl_xor(l_pL, 32);
    l_pH += __shfl_xor(l_pH, 16);
    l_pH += __shfl_xor(l_pH, 32);
    if (quad == 0) {
        Lw[wave][l16] = l_pL;
        Lw[wave][16 + l16] = l_pH;
    }
    __syncthreads();

    // ---- epilogue: normalize, gamma, residual (no merge needed)
    {
        const float g = gamma[0];
        float linv[2][4];
#pragma unroll
        for (int h = 0; h < 2; h++)
#pragma unroll
            for (int r = 0; r < 4; r++)
                linv[h][r] = g / Lw[wave][h * 16 + quad * 4 + r];
#pragma unroll
        for (int t = 0; t < 16; t++) {
            const int c = t * 16 + l16;
#pragma unroll
            for (int h = 0; h < 2; h++) {
                const int nb = q0 + h * 16 + quad * 4;
                f32x4 o1 = h ? oH[t] : oL[t];
                f32x4 ov;
#pragma unroll
                for (int r = 0; r < 4; r++) ov[r] = o1[r] * linv[h][r];
                size_t idx = ((size_t)(b * C + c)) * N + nb;
                f32x4 xv = *(const f32x4*)(x + idx);
                *(f32x4*)(out + idx) = ov + xv;
            }
        }
    }
}

extern "C" void kernel_launch(void* const* d_in, const int* in_sizes, int n_in,
                              void* d_out, int out_size, void* d_ws, size_t ws_size,
                              hipStream_t stream) {
    const int B = 8, C = 256, N = 4096;
    const float* x     = (const float*)d_in[0];
    const float* wq    = (const float*)d_in[1];
    const float* bq    = (const float*)d_in[2];
    const float* wk    = (const float*)d_in[3];
    const float* bk    = (const float*)d_in[4];
    const float* wv    = (const float*)d_in[5];
    const float* bv    = (const float*)d_in[6];
    const float* gamma = (const float*)d_in[7];
    float* out = (float*)d_out;

    unsigned short* Qc = (unsigned short*)d_ws;             // [B][C][N] bf16 (x log2e), pair-interleaved
    unsigned short* Kr = Qc + (size_t)B * C * N;            // [B][N][C] bf16
    unsigned short* Vc = Kr + (size_t)B * N * C;            // [B][C][N] bf16, pair-interleaved
    unsigned short* Wb = Vc + (size_t)B * C * N;            // [3][256][256] bf16

    wcvt_kernel<<<dim3(192), 256, 0, stream>>>(wq, wk, wv, Wb);
    qkv_kernel<<<dim3(1024), 256, 0, stream>>>(x, Wb, bq, bk, bv, Qc, Kr, Vc);
    attn_kernel<<<dim3(256), 256, 0, stream>>>(Qc, Kr, Vc, x, gamma, out);
}

// Round 5
// 362.524 us; speedup vs baseline: 1.3619x; 1.3619x over previous
//
#include <hip/hip_runtime.h>
#include <hip/hip_bf16.h>
#include <cstdint>

// B=8, C=256, N=4096 spatial self-attention.
// R9 = R7 shell (512 thr, 8 waves, in-block key-split, 64 iters, 1 block/CU)
// + (1) V-read rotation bank fix proven in R8 (conflicts 8.9M -> 0):
//   read slot sigma=(quad+(l16>>1))&3, global source pre-rotated, LDS linear.
// + (2) MFMA clustering pipeline: iter i runs softmax(i) -> barrier(stage i+1
//   landed) -> QK(i+1) + PV(i) back-to-back (independent MFMA clusters) ->
//   barrier -> stage(i+2). MFMA pipe no longer idles during softmax.
// Keeps: swapped QK^T w/ lane-local P (zero P LDS), DPP wave-max,
// defer-rescale THR=8, Q/V pair-interleave, XOR-swizzled K staging, 3-pass qkv.

typedef short short8 __attribute__((ext_vector_type(8)));
typedef short short4v __attribute__((ext_vector_type(4)));
typedef float f32x4 __attribute__((ext_vector_type(4)));
typedef unsigned int uint4v __attribute__((ext_vector_type(4)));

#define MFMA16(a, b, c) __builtin_amdgcn_mfma_f32_16x16x32_bf16((a), (b), (c), 0, 0, 0)
#define LOG2E 1.4426950408889634f

__device__ __forceinline__ unsigned short f2bf(float f) {
    union { float f; unsigned int u; } v;
    v.f = f;
    unsigned int u = v.u;
    return (unsigned short)((u + 0x7fffu + ((u >> 16) & 1u)) >> 16);
}

__device__ __forceinline__ void load_lds16(const unsigned short* g, unsigned short* l) {
    __builtin_amdgcn_global_load_lds(
        (const __attribute__((address_space(1))) unsigned int*)g,
        (__attribute__((address_space(3))) unsigned int*)l, 16, 0, 0);
}

// max over the 16-lane row group via DPP row_ror (VALU only, no LDS unit)
__device__ __forceinline__ float rowmax16_dpp(float x) {
    int v;
    v = __builtin_amdgcn_update_dpp(0, __float_as_int(x), 0x121, 0xf, 0xf, false);
    x = fmaxf(x, __int_as_float(v));
    v = __builtin_amdgcn_update_dpp(0, __float_as_int(x), 0x122, 0xf, 0xf, false);
    x = fmaxf(x, __int_as_float(v));
    v = __builtin_amdgcn_update_dpp(0, __float_as_int(x), 0x124, 0xf, 0xf, false);
    x = fmaxf(x, __int_as_float(v));
    v = __builtin_amdgcn_update_dpp(0, __float_as_int(x), 0x128, 0xf, 0xf, false);
    x = fmaxf(x, __int_as_float(v));
    return x;
}

// 16-group maxes -> full-wave max broadcast, VALU-only (row_bcast15/31 + readlane)
__device__ __forceinline__ float wavemax_bcast(float x) {
    int v;
    v = __builtin_amdgcn_update_dpp(__float_as_int(x), __float_as_int(x), 0x142, 0xf, 0xf, false);
    x = fmaxf(x, __int_as_float(v));
    v = __builtin_amdgcn_update_dpp(__float_as_int(x), __float_as_int(x), 0x143, 0xf, 0xf, false);
    x = fmaxf(x, __int_as_float(v));
    return __int_as_float(__builtin_amdgcn_readlane(__float_as_int(x), 63));
}

// ---------------- Kernel 0: weight fp32 -> bf16 ------------------------------
__global__ __launch_bounds__(256) void wcvt_kernel(
    const float* __restrict__ wq, const float* __restrict__ wk,
    const float* __restrict__ wv, unsigned short* __restrict__ Wb)
{
    int idx = (blockIdx.x * 256 + threadIdx.x) * 4;
    const float* src = (idx < 65536) ? wq : ((idx < 131072) ? wk : wv);
    float4 f = *(const float4*)(src + (idx & 65535));
    short4v s = { (short)f2bf(f.x), (short)f2bf(f.y), (short)f2bf(f.z), (short)f2bf(f.w) };
    *(short4v*)(Wb + idx) = s;
}

// ---------------- Kernel 1: QKV projection via MFMA --------------------------
// 1024 blocks x 256 thr (4 waves). Block: batch b, 32 tokens; wave: 64 channels.
// Three sequential passes (Q, V, K). Qc AND Vc both [B][C][N] bf16,
// pair-interleaved per 32-token chunk: u32 slot a <- tokens (a, a+16).
// Q pre-scaled by log2e. Kr [B][N][C].
__global__ __launch_bounds__(256, 2) void qkv_kernel(
    const float* __restrict__ x, const unsigned short* __restrict__ Wb,
    const float* __restrict__ bq, const float* __restrict__ bk,
    const float* __restrict__ bv,
    unsigned short* __restrict__ Qc, unsigned short* __restrict__ Kr,
    unsigned short* __restrict__ Vc)
{
    const int C = 256, N = 4096;
    __shared__ __align__(16) unsigned short Xt[32][264];   // [token][c], pad 264

    const int tid  = threadIdx.x;
    const int bid  = blockIdx.x;
    const int b    = bid >> 7;
    const int n0   = (bid & 127) * 32;
    const int wave = tid >> 6;
    const int lane = tid & 63;
    const int quad = lane >> 4;
    const int l16  = lane & 15;
    const int ch0  = wave * 64;

    // stage X^T tile: fp32 [c][token] -> bf16 LDS [token][c]
    {
        const int token = tid & 31;
        const int cg    = tid >> 5;
        const float* xb = x + ((size_t)b * C) * N + n0 + token;
#pragma unroll
        for (int p = 0; p < 8; p++) {
            int c0 = p * 32 + cg * 4;
            float f0 = xb[(size_t)(c0 + 0) * N];
            float f1 = xb[(size_t)(c0 + 1) * N];
            float f2 = xb[(size_t)(c0 + 2) * N];
            float f3 = xb[(size_t)(c0 + 3) * N];
            short4v s = { (short)f2bf(f0), (short)f2bf(f1), (short)f2bf(f2), (short)f2bf(f3) };
            *(short4v*)(&Xt[token][c0]) = s;
        }
    }
    __syncthreads();

    f32x4 acc[4][2];

    // ---------------- pass 0: Q (m=0), scaled by log2e, pair-interleaved -----
#pragma unroll
    for (int ct = 0; ct < 4; ct++)
#pragma unroll
        for (int tt = 0; tt < 2; tt++) acc[ct][tt] = (f32x4){0.f, 0.f, 0.f, 0.f};
#pragma unroll
    for (int kc = 0; kc < 8; kc++) {
        const int ko = kc * 32 + quad * 8;
        short8 ax0 = *(const short8*)(&Xt[l16][ko]);
        short8 ax1 = *(const short8*)(&Xt[16 + l16][ko]);
#pragma unroll
        for (int ct = 0; ct < 4; ct++) {
            short8 wf = *(const short8*)(Wb + (ch0 + ct * 16 + l16) * 256 + ko);
            acc[ct][0] = MFMA16(ax0, wf, acc[ct][0]);
            acc[ct][1] = MFMA16(ax1, wf, acc[ct][1]);
        }
    }
#pragma unroll
    for (int ct = 0; ct < 4; ct++) {
        const int ch = ch0 + ct * 16 + l16;
        const float biq = bq[ch];
        uint4v qv;
#pragma unroll
        for (int r = 0; r < 4; r++) {
            unsigned int lo = f2bf((acc[ct][0][r] + biq) * LOG2E);   // token quad*4+r
            unsigned int hi = f2bf((acc[ct][1][r] + biq) * LOG2E);   // token quad*4+r+16
            qv[r] = lo | (hi << 16);
        }
        *(uint4v*)(Qc + ((size_t)b * C + ch) * N + n0 + quad * 8) = qv;
    }

    // ---------------- pass 1: V (m=2), pair-interleaved b128 stores ----------
#pragma unroll
    for (int ct = 0; ct < 4; ct++)
#pragma unroll
        for (int tt = 0; tt < 2; tt++) acc[ct][tt] = (f32x4){0.f, 0.f, 0.f, 0.f};
#pragma unroll
    for (int kc = 0; kc < 8; kc++) {
        const int ko = kc * 32 + quad * 8;
        short8 ax0 = *(const short8*)(&Xt[l16][ko]);
        short8 ax1 = *(const short8*)(&Xt[16 + l16][ko]);
#pragma unroll
        for (int ct = 0; ct < 4; ct++) {
            short8 wf = *(const short8*)(Wb + (2 << 16) + (ch0 + ct * 16 + l16) * 256 + ko);
            acc[ct][0] = MFMA16(ax0, wf, acc[ct][0]);
            acc[ct][1] = MFMA16(ax1, wf, acc[ct][1]);
        }
    }
#pragma unroll
    for (int ct = 0; ct < 4; ct++) {
        const int ch = ch0 + ct * 16 + l16;
        const float biv = bv[ch];
        uint4v vv;
#pragma unroll
        for (int r = 0; r < 4; r++) {
            unsigned int lo = f2bf(acc[ct][0][r] + biv);
            unsigned int hi = f2bf(acc[ct][1][r] + biv);
            vv[r] = lo | (hi << 16);
        }
        *(uint4v*)(Vc + ((size_t)b * C + ch) * N + n0 + quad * 8) = vv;
    }

    // ---------------- pass 2: K (m=1), transpose via LDS ----------------
#pragma unroll
    for (int ct = 0; ct < 4; ct++)
#pragma unroll
        for (int tt = 0; tt < 2; tt++) acc[ct][tt] = (f32x4){0.f, 0.f, 0.f, 0.f};
#pragma unroll
    for (int kc = 0; kc < 8; kc++) {
        const int ko = kc * 32 + quad * 8;
        short8 ax0 = *(const short8*)(&Xt[l16][ko]);
        short8 ax1 = *(const short8*)(&Xt[16 + l16][ko]);
#pragma unroll
        for (int ct = 0; ct < 4; ct++) {
            short8 wf = *(const short8*)(Wb + (1 << 16) + (ch0 + ct * 16 + l16) * 256 + ko);
            acc[ct][0] = MFMA16(ax0, wf, acc[ct][0]);
            acc[ct][1] = MFMA16(ax1, wf, acc[ct][1]);
        }
    }
    __syncthreads();    // Xt reads all done (all passes)
#pragma unroll
    for (int ct = 0; ct < 4; ct++) {
        const int ch = ch0 + ct * 16 + l16;
        const float bik = bk[ch];
#pragma unroll
        for (int tt = 0; tt < 2; tt++) {
#pragma unroll
            for (int r = 0; r < 4; r++)
                Xt[tt * 16 + quad * 4 + r][ch] = f2bf(acc[ct][tt][r] + bik);
        }
    }
    __syncthreads();
#pragma unroll
    for (int p = 0; p < 2; p++) {
        int chunk = p * 256 + tid;          // 0..511
        int tok = chunk >> 4;
        int cc  = (chunk & 15) * 16;
        *(short8*)(Kr + ((size_t)b * N + n0 + tok) * C + cc) = *(const short8*)(&Xt[tok][cc]);
    }
}

// ---------------- Kernel 2: flash attention + epilogue -----------------------
// 256 blocks x 512 thr (8 waves, 2/SIMD). b = bid&7, q-block = (bid>>3)*128.
// Wave w: queries q0 = qblk + (w&3)*32 (halves L/H of 16), keys
// [(w>>2)*2048, +2048) in 64 iters of KT=32; in-block LDS merge at end.
// Pipeline: iter i = softmax(i) -> sync(stage i+1 landed) -> QK(i+1)+PV(i)
// (back-to-back MFMA clusters) -> sync -> stage(i+2).
// V LDS: row c (64B); read slot sigma=(quad+(l16>>1))&3 rotation, source
// pre-rotated j=(s-(c>>1))&3 (LDS dst linear for global_load_lds). 0 conflicts.
__global__ __launch_bounds__(512, 2) void attn_kernel(
    const unsigned short* __restrict__ Qc,
    const unsigned short* __restrict__ Kr,
    const unsigned short* __restrict__ Vc,
    const float* __restrict__ x,
    const float* __restrict__ gamma,
    float* __restrict__ out)
{
    const int C = 256, N = 4096;
    __shared__ __align__(16) unsigned short KV[2][32768];   // 128 KB
    __shared__ float Lw[8][32];                              // per-wave l by query
    __shared__ float MwL[4];

    const int tid  = threadIdx.x;
    const int wave = tid >> 6;
    const int ks   = wave >> 2;          // key-split half
    const int w4   = wave & 3;
    const int lane = tid & 63;
    const int quad = lane >> 4;
    const int l16  = lane & 15;
    const int bid  = blockIdx.x;
    const int b    = bid & 7;
    const int q0   = (bid >> 3) * 128 + w4 * 32;

    const unsigned short* kb  = Kr + (size_t)b * N * C;
    const unsigned short* vcb = Vc + (size_t)b * C * N;

    // Q fragments (B-operand): one u32 per (ch, pair l16) = tokens (q0+l16, +16)
    short8 aqL[8], aqH[8];
    {
        const unsigned int* qb32 = (const unsigned int*)(Qc + (size_t)b * C * N);
#pragma unroll
        for (int f = 0; f < 8; f++) {
#pragma unroll
            for (int j = 0; j < 8; j++) {
                size_t i32 = ((size_t)(f * 32 + quad * 8 + j) * N + q0) / 2 + l16;
                unsigned int u = qb32[i32];
                aqL[f][j] = (short)(u & 0xffff);
                aqH[f][j] = (short)(u >> 16);
            }
        }
    }

    f32x4 oL[16], oH[16];
#pragma unroll
    for (int t = 0; t < 16; t++) {
        oL[t] = (f32x4){0.f, 0.f, 0.f, 0.f};
        oH[t] = (f32x4){0.f, 0.f, 0.f, 0.f};
    }
    float m_w = -__builtin_inff();
    float l_pL = 0.f, l_pH = 0.f;        // partial l for query l16 (+16 for H)

    // stage both key-halves' K/V tiles (block-wide)
    auto stage = [&](int buf, int m0) {
        unsigned short* dst = &KV[buf][0];
#pragma unroll
        for (int p = 0; p < 4; p++) {               // K: 2048 chunks
            int chunk = p * 512 + tid;
            int half = chunk >> 10;
            int idx  = chunk & 1023;
            int key = idx >> 5;
            int j = (idx & 31) ^ (key & 31);
            load_lds16(kb + (size_t)(half * 2048 + m0 + key) * C + j * 8,
                       dst + half * 16384 + idx * 8);
        }
#pragma unroll
        for (int p = 0; p < 4; p++) {               // V: 2048 chunks
            int chunk = p * 512 + tid;
            int half = chunk >> 10;
            int idx  = chunk & 1023;
            int c = idx >> 2;
            int s = idx & 3;
            int j = (s - (c >> 1)) & 3;             // source pre-rotation
            load_lds16(vcb + (size_t)c * N + half * 2048 + m0 + j * 8,
                       dst + half * 16384 + 8192 + idx * 8);
        }
    };

    // S^T tile registers (persist across the pipeline boundary)
    f32x4 tL0, tL1, tH0, tH1;

    // QK cluster: S^T = K Q^T for tile in KV[buf]
    auto qk = [&](int buf) {
        const unsigned short* Kb = &KV[buf][ks * 16384];
        f32x4 a0 = {0.f,0.f,0.f,0.f}, a1 = {0.f,0.f,0.f,0.f};
        f32x4 b0 = {0.f,0.f,0.f,0.f}, b1 = {0.f,0.f,0.f,0.f};
#pragma unroll
        for (int f = 0; f < 8; f++) {
            const int j = f * 4 + quad;
            int k0 = l16, k1 = 16 + l16;
            short8 kf0 = *(const short8*)(Kb + (k0 * 32 + (j ^ (k0 & 31))) * 8);
            short8 kf1 = *(const short8*)(Kb + (k1 * 32 + (j ^ (k1 & 31))) * 8);
            a0 = MFMA16(kf0, aqL[f], a0);
            a1 = MFMA16(kf1, aqL[f], a1);
            b0 = MFMA16(kf0, aqH[f], b0);
            b1 = MFMA16(kf1, aqH[f], b1);
        }
        tL0 = a0; tL1 = a1; tH0 = b0; tH1 = b1;
    };

    const int vsl = ((quad + (l16 >> 1)) & 3) * 8;  // V read slot (lane-const)

    stage(0, 0);
    __syncthreads();            // stage(0) landed
    stage(1, 32);               // in flight through QK(0)+softmax(0)
    qk(0);

    for (int it = 0; it < 64; ++it) {
        // ---- softmax(it): wave-wide online max (base-2; VALU-only)
        float mx = fmaxf(fmaxf(fmaxf(tL0[0], tL0[1]), fmaxf(tL0[2], tL0[3])),
                         fmaxf(fmaxf(tL1[0], tL1[1]), fmaxf(tL1[2], tL1[3])));
        mx = fmaxf(mx, fmaxf(fmaxf(fmaxf(tH0[0], tH0[1]), fmaxf(tH0[2], tH0[3])),
                             fmaxf(fmaxf(tH1[0], tH1[1]), fmaxf(tH1[2], tH1[3]))));
        mx = rowmax16_dpp(mx);
        mx = wavemax_bcast(mx);

        // defer-rescale (T13): only pay the rescale when max grows by >8
        if (mx > m_w + 8.0f) {
            const float al = exp2f(m_w - mx);   // 0 on first iter
            m_w = mx;
            l_pL *= al; l_pH *= al;
#pragma unroll
            for (int t = 0; t < 16; t++) { oL[t] *= al; oH[t] *= al; }
        }
        const float mn = m_w;

        // exps -> lane-local PV A-fragments (zero LDS)
        uint4v apLu, apHu;
#pragma unroll
        for (int w = 0; w < 4; w++) {
            float e0 = exp2f(tL0[w] - mn);
            float e1 = exp2f(tL1[w] - mn);
            l_pL += e0 + e1;
            union { __hip_bfloat162 v; unsigned int u; } cv;
            cv.v = __float22bfloat162_rn(float2{e0, e1});
            apLu[w] = cv.u;
            float g0 = exp2f(tH0[w] - mn);
            float g1 = exp2f(tH1[w] - mn);
            l_pH += g0 + g1;
            union { __hip_bfloat162 v; unsigned int u; } cw;
            cw.v = __float22bfloat162_rn(float2{g0, g1});
            apHu[w] = cw.u;
        }
        short8 apL, apH;
        {
            union { uint4v u; short8 s; } c1; c1.u = apLu; apL = c1.s;
            union { uint4v u; short8 s; } c2; c2.u = apHu; apH = c2.s;
        }

        // ---- pipeline: QK(it+1) then PV(it) -- independent MFMA clusters
        if (it < 63) {
            __syncthreads();        // stage(it+1) landed (vmcnt drained here)
            qk((it + 1) & 1);       // overwrites tL/tH for next iter
        }

        {   // PV(it): 16 channel-tiles from KV[it&1]
            const unsigned short* Vb = &KV[it & 1][ks * 16384 + 8192];
#pragma unroll
            for (int t = 0; t < 16; t++) {
                short8 vf = *(const short8*)(Vb + t * 512 + l16 * 32 + vsl);
                oL[t] = MFMA16(apL, vf, oL[t]);
                oH[t] = MFMA16(apH, vf, oH[t]);
            }
        }
        __syncthreads();            // all reads of KV[it&1] done
        if (it < 62) stage(it & 1, (it + 2) * 32);
    }

    // ---- reduce l partials across quads (keys split over the 4 quad-lanes)
    l_pL += __shfl_xor(l_pL, 16);
    l_pL += __shfl_xor(l_pL, 32);
    l_pH += __shfl_xor(l_pH, 16);
    l_pH += __shfl_xor(l_pH, 32);
    if (quad == 0) {
        Lw[wave][l16] = l_pL;
        Lw[wave][16 + l16] = l_pH;
    }

    // ---- in-block merge of the two key-halves
    float* CombF = (float*)(&KV[0][0]);   // 4 waves x 32 q x 256 c f32 = 128 KB
    __syncthreads();                       // loop reads done + Lw visible
    if (ks == 1) {
#pragma unroll
        for (int t = 0; t < 16; t++) {
#pragma unroll
            for (int r = 0; r < 4; r++) {
                CombF[(size_t)(w4 * 32 + quad * 4 + r) * 256 + t * 16 + l16] = oL[t][r];
                CombF[(size_t)(w4 * 32 + 16 + quad * 4 + r) * 256 + t * 16 + l16] = oH[t][r];
            }
        }
        if (lane == 0) MwL[w4] = m_w;
    }
    __syncthreads();
    if (ks == 0) {
        const float g = gamma[0];
        const float m2w = MwL[w4];
        const float mt = fmaxf(m_w, m2w);
        const float f1 = exp2f(m_w - mt);
        const float f2 = exp2f(m2w - mt);
        float linv[2][4];
#pragma unroll
        for (int h = 0; h < 2; h++)
#pragma unroll
            for (int r = 0; r < 4; r++) {
                const int q = h * 16 + quad * 4 + r;
                linv[h][r] = g / (Lw[w4][q] * f1 + Lw[4 + w4][q] * f2);
            }
#pragma unroll
        for (int t = 0; t < 16; t++) {
            const int c = t * 16 + l16;
#pragma unroll
            for (int h = 0; h < 2; h++) {
                const int nb = q0 + h * 16 + quad * 4;
                f32x4 o1 = h ? oH[t] : oL[t];
                f32x4 ov;
#pragma unroll
                for (int r = 0; r < 4; r++) {
                    float o2 = CombF[(size_t)(w4 * 32 + h * 16 + quad * 4 + r) * 256 + c];
                    ov[r] = (o1[r] * f1 + o2 * f2) * linv[h][r];
                }
                size_t idx = ((size_t)(b * C + c)) * N + nb;
                f32x4 xv = *(const f32x4*)(x + idx);
                *(f32x4*)(out + idx) = ov + xv;
            }
        }
    }
}

extern "C" void kernel_launch(void* const* d_in, const int* in_sizes, int n_in,
                              void* d_out, int out_size, void* d_ws, size_t ws_size,
                              hipStream_t stream) {
    const int B = 8, C = 256, N = 4096;
    const float* x     = (const float*)d_in[0];
    const float* wq    = (const float*)d_in[1];
    const float* bq    = (const float*)d_in[2];
    const float* wk    = (const float*)d_in[3];
    const float* bk    = (const float*)d_in[4];
    const float* wv    = (const float*)d_in[5];
    const float* bv    = (const float*)d_in[6];
    const float* gamma = (const float*)d_in[7];
    float* out = (float*)d_out;

    unsigned short* Qc = (unsigned short*)d_ws;             // [B][C][N] bf16 (x log2e), pair-interleaved
    unsigned short* Kr = Qc + (size_t)B * C * N;            // [B][N][C] bf16
    unsigned short* Vc = Kr + (size_t)B * N * C;            // [B][C][N] bf16, pair-interleaved
    unsigned short* Wb = Vc + (size_t)B * C * N;            // [3][256][256] bf16

    wcvt_kernel<<<dim3(192), 256, 0, stream>>>(wq, wk, wv, Wb);
    qkv_kernel<<<dim3(1024), 256, 0, stream>>>(x, Wb, bq, bk, bv, Qc, Kr, Vc);
    attn_kernel<<<dim3(256), 512, 0, stream>>>(Qc, Kr, Vc, x, gamma, out);
}

// Round 6
// 360.494 us; speedup vs baseline: 1.3696x; 1.0056x over previous
//
#include <hip/hip_runtime.h>
#include <hip/hip_bf16.h>
#include <cstdint>

// B=8, C=256, N=4096 spatial self-attention.
// R10 = R9 with the attn K-loop re-scheduled to ONE barrier per iteration:
//   softmax(it) -> PV(it) -> sync -> stage(it+2) -> qk(it+1)
// The single barrier serves both hazards (stage(it+1) landed for qk(it+1);
// PV(it) done reading buf it&1 before stage(it+2) overwrites it). stage's
// global_load_lds now has qk+softmax+PV (~1500 cyc) to land instead of just
// softmax (~250 cyc) -> barrier drain stalls eliminated; barriers/iter 2 -> 1.
// Keeps: V-read rotation (conflicts ~0), swapped QK^T w/ lane-local P, DPP
// wave-max, defer-rescale THR=8, Q/V pair-interleave, XOR K staging, 3-pass qkv.

typedef short short8 __attribute__((ext_vector_type(8)));
typedef short short4v __attribute__((ext_vector_type(4)));
typedef float f32x4 __attribute__((ext_vector_type(4)));
typedef unsigned int uint4v __attribute__((ext_vector_type(4)));

#define MFMA16(a, b, c) __builtin_amdgcn_mfma_f32_16x16x32_bf16((a), (b), (c), 0, 0, 0)
#define LOG2E 1.4426950408889634f

__device__ __forceinline__ unsigned short f2bf(float f) {
    union { float f; unsigned int u; } v;
    v.f = f;
    unsigned int u = v.u;
    return (unsigned short)((u + 0x7fffu + ((u >> 16) & 1u)) >> 16);
}

__device__ __forceinline__ void load_lds16(const unsigned short* g, unsigned short* l) {
    __builtin_amdgcn_global_load_lds(
        (const __attribute__((address_space(1))) unsigned int*)g,
        (__attribute__((address_space(3))) unsigned int*)l, 16, 0, 0);
}

// max over the 16-lane row group via DPP row_ror (VALU only, no LDS unit)
__device__ __forceinline__ float rowmax16_dpp(float x) {
    int v;
    v = __builtin_amdgcn_update_dpp(0, __float_as_int(x), 0x121, 0xf, 0xf, false);
    x = fmaxf(x, __int_as_float(v));
    v = __builtin_amdgcn_update_dpp(0, __float_as_int(x), 0x122, 0xf, 0xf, false);
    x = fmaxf(x, __int_as_float(v));
    v = __builtin_amdgcn_update_dpp(0, __float_as_int(x), 0x124, 0xf, 0xf, false);
    x = fmaxf(x, __int_as_float(v));
    v = __builtin_amdgcn_update_dpp(0, __float_as_int(x), 0x128, 0xf, 0xf, false);
    x = fmaxf(x, __int_as_float(v));
    return x;
}

// 16-group maxes -> full-wave max broadcast, VALU-only (row_bcast15/31 + readlane)
__device__ __forceinline__ float wavemax_bcast(float x) {
    int v;
    v = __builtin_amdgcn_update_dpp(__float_as_int(x), __float_as_int(x), 0x142, 0xf, 0xf, false);
    x = fmaxf(x, __int_as_float(v));
    v = __builtin_amdgcn_update_dpp(__float_as_int(x), __float_as_int(x), 0x143, 0xf, 0xf, false);
    x = fmaxf(x, __int_as_float(v));
    return __int_as_float(__builtin_amdgcn_readlane(__float_as_int(x), 63));
}

// ---------------- Kernel 0: weight fp32 -> bf16 ------------------------------
__global__ __launch_bounds__(256) void wcvt_kernel(
    const float* __restrict__ wq, const float* __restrict__ wk,
    const float* __restrict__ wv, unsigned short* __restrict__ Wb)
{
    int idx = (blockIdx.x * 256 + threadIdx.x) * 4;
    const float* src = (idx < 65536) ? wq : ((idx < 131072) ? wk : wv);
    float4 f = *(const float4*)(src + (idx & 65535));
    short4v s = { (short)f2bf(f.x), (short)f2bf(f.y), (short)f2bf(f.z), (short)f2bf(f.w) };
    *(short4v*)(Wb + idx) = s;
}

// ---------------- Kernel 1: QKV projection via MFMA --------------------------
// 1024 blocks x 256 thr (4 waves). Block: batch b, 32 tokens; wave: 64 channels.
// Three sequential passes (Q, V, K). Qc AND Vc both [B][C][N] bf16,
// pair-interleaved per 32-token chunk: u32 slot a <- tokens (a, a+16).
// Q pre-scaled by log2e. Kr [B][N][C].
__global__ __launch_bounds__(256, 2) void qkv_kernel(
    const float* __restrict__ x, const unsigned short* __restrict__ Wb,
    const float* __restrict__ bq, const float* __restrict__ bk,
    const float* __restrict__ bv,
    unsigned short* __restrict__ Qc, unsigned short* __restrict__ Kr,
    unsigned short* __restrict__ Vc)
{
    const int C = 256, N = 4096;
    __shared__ __align__(16) unsigned short Xt[32][264];   // [token][c], pad 264

    const int tid  = threadIdx.x;
    const int bid  = blockIdx.x;
    const int b    = bid >> 7;
    const int n0   = (bid & 127) * 32;
    const int wave = tid >> 6;
    const int lane = tid & 63;
    const int quad = lane >> 4;
    const int l16  = lane & 15;
    const int ch0  = wave * 64;

    // stage X^T tile: fp32 [c][token] -> bf16 LDS [token][c]
    {
        const int token = tid & 31;
        const int cg    = tid >> 5;
        const float* xb = x + ((size_t)b * C) * N + n0 + token;
#pragma unroll
        for (int p = 0; p < 8; p++) {
            int c0 = p * 32 + cg * 4;
            float f0 = xb[(size_t)(c0 + 0) * N];
            float f1 = xb[(size_t)(c0 + 1) * N];
            float f2 = xb[(size_t)(c0 + 2) * N];
            float f3 = xb[(size_t)(c0 + 3) * N];
            short4v s = { (short)f2bf(f0), (short)f2bf(f1), (short)f2bf(f2), (short)f2bf(f3) };
            *(short4v*)(&Xt[token][c0]) = s;
        }
    }
    __syncthreads();

    f32x4 acc[4][2];

    // ---------------- pass 0: Q (m=0), scaled by log2e, pair-interleaved -----
#pragma unroll
    for (int ct = 0; ct < 4; ct++)
#pragma unroll
        for (int tt = 0; tt < 2; tt++) acc[ct][tt] = (f32x4){0.f, 0.f, 0.f, 0.f};
#pragma unroll
    for (int kc = 0; kc < 8; kc++) {
        const int ko = kc * 32 + quad * 8;
        short8 ax0 = *(const short8*)(&Xt[l16][ko]);
        short8 ax1 = *(const short8*)(&Xt[16 + l16][ko]);
#pragma unroll
        for (int ct = 0; ct < 4; ct++) {
            short8 wf = *(const short8*)(Wb + (ch0 + ct * 16 + l16) * 256 + ko);
            acc[ct][0] = MFMA16(ax0, wf, acc[ct][0]);
            acc[ct][1] = MFMA16(ax1, wf, acc[ct][1]);
        }
    }
#pragma unroll
    for (int ct = 0; ct < 4; ct++) {
        const int ch = ch0 + ct * 16 + l16;
        const float biq = bq[ch];
        uint4v qv;
#pragma unroll
        for (int r = 0; r < 4; r++) {
            unsigned int lo = f2bf((acc[ct][0][r] + biq) * LOG2E);   // token quad*4+r
            unsigned int hi = f2bf((acc[ct][1][r] + biq) * LOG2E);   // token quad*4+r+16
            qv[r] = lo | (hi << 16);
        }
        *(uint4v*)(Qc + ((size_t)b * C + ch) * N + n0 + quad * 8) = qv;
    }

    // ---------------- pass 1: V (m=2), pair-interleaved b128 stores ----------
#pragma unroll
    for (int ct = 0; ct < 4; ct++)
#pragma unroll
        for (int tt = 0; tt < 2; tt++) acc[ct][tt] = (f32x4){0.f, 0.f, 0.f, 0.f};
#pragma unroll
    for (int kc = 0; kc < 8; kc++) {
        const int ko = kc * 32 + quad * 8;
        short8 ax0 = *(const short8*)(&Xt[l16][ko]);
        short8 ax1 = *(const short8*)(&Xt[16 + l16][ko]);
#pragma unroll
        for (int ct = 0; ct < 4; ct++) {
            short8 wf = *(const short8*)(Wb + (2 << 16) + (ch0 + ct * 16 + l16) * 256 + ko);
            acc[ct][0] = MFMA16(ax0, wf, acc[ct][0]);
            acc[ct][1] = MFMA16(ax1, wf, acc[ct][1]);
        }
    }
#pragma unroll
    for (int ct = 0; ct < 4; ct++) {
        const int ch = ch0 + ct * 16 + l16;
        const float biv = bv[ch];
        uint4v vv;
#pragma unroll
        for (int r = 0; r < 4; r++) {
            unsigned int lo = f2bf(acc[ct][0][r] + biv);
            unsigned int hi = f2bf(acc[ct][1][r] + biv);
            vv[r] = lo | (hi << 16);
        }
        *(uint4v*)(Vc + ((size_t)b * C + ch) * N + n0 + quad * 8) = vv;
    }

    // ---------------- pass 2: K (m=1), transpose via LDS ----------------
#pragma unroll
    for (int ct = 0; ct < 4; ct++)
#pragma unroll
        for (int tt = 0; tt < 2; tt++) acc[ct][tt] = (f32x4){0.f, 0.f, 0.f, 0.f};
#pragma unroll
    for (int kc = 0; kc < 8; kc++) {
        const int ko = kc * 32 + quad * 8;
        short8 ax0 = *(const short8*)(&Xt[l16][ko]);
        short8 ax1 = *(const short8*)(&Xt[16 + l16][ko]);
#pragma unroll
        for (int ct = 0; ct < 4; ct++) {
            short8 wf = *(const short8*)(Wb + (1 << 16) + (ch0 + ct * 16 + l16) * 256 + ko);
            acc[ct][0] = MFMA16(ax0, wf, acc[ct][0]);
            acc[ct][1] = MFMA16(ax1, wf, acc[ct][1]);
        }
    }
    __syncthreads();    // Xt reads all done (all passes)
#pragma unroll
    for (int ct = 0; ct < 4; ct++) {
        const int ch = ch0 + ct * 16 + l16;
        const float bik = bk[ch];
#pragma unroll
        for (int tt = 0; tt < 2; tt++) {
#pragma unroll
            for (int r = 0; r < 4; r++)
                Xt[tt * 16 + quad * 4 + r][ch] = f2bf(acc[ct][tt][r] + bik);
        }
    }
    __syncthreads();
#pragma unroll
    for (int p = 0; p < 2; p++) {
        int chunk = p * 256 + tid;          // 0..511
        int tok = chunk >> 4;
        int cc  = (chunk & 15) * 16;
        *(short8*)(Kr + ((size_t)b * N + n0 + tok) * C + cc) = *(const short8*)(&Xt[tok][cc]);
    }
}

// ---------------- Kernel 2: flash attention + epilogue -----------------------
// 256 blocks x 512 thr (8 waves, 2/SIMD). b = bid&7, q-block = (bid>>3)*128.
// Wave w: queries q0 = qblk + (w&3)*32 (halves L/H of 16), keys
// [(w>>2)*2048, +2048) in 64 iters of KT=32; in-block LDS merge at end.
// Loop (1 barrier/iter): softmax(it) -> PV(it) -> sync -> stage(it+2) ->
// qk(it+1). The sync covers both hazards; staged loads get ~3 phases to land.
// V LDS: row c (64B); read slot sigma=(quad+(l16>>1))&3 rotation, source
// pre-rotated j=(s-(c>>1))&3 (LDS dst linear for global_load_lds). 0 conflicts.
__global__ __launch_bounds__(512, 2) void attn_kernel(
    const unsigned short* __restrict__ Qc,
    const unsigned short* __restrict__ Kr,
    const unsigned short* __restrict__ Vc,
    const float* __restrict__ x,
    const float* __restrict__ gamma,
    float* __restrict__ out)
{
    const int C = 256, N = 4096;
    __shared__ __align__(16) unsigned short KV[2][32768];   // 128 KB
    __shared__ float Lw[8][32];                              // per-wave l by query
    __shared__ float MwL[4];

    const int tid  = threadIdx.x;
    const int wave = tid >> 6;
    const int ks   = wave >> 2;          // key-split half
    const int w4   = wave & 3;
    const int lane = tid & 63;
    const int quad = lane >> 4;
    const int l16  = lane & 15;
    const int bid  = blockIdx.x;
    const int b    = bid & 7;
    const int q0   = (bid >> 3) * 128 + w4 * 32;

    const unsigned short* kb  = Kr + (size_t)b * N * C;
    const unsigned short* vcb = Vc + (size_t)b * C * N;

    // Q fragments (B-operand): one u32 per (ch, pair l16) = tokens (q0+l16, +16)
    short8 aqL[8], aqH[8];
    {
        const unsigned int* qb32 = (const unsigned int*)(Qc + (size_t)b * C * N);
#pragma unroll
        for (int f = 0; f < 8; f++) {
#pragma unroll
            for (int j = 0; j < 8; j++) {
                size_t i32 = ((size_t)(f * 32 + quad * 8 + j) * N + q0) / 2 + l16;
                unsigned int u = qb32[i32];
                aqL[f][j] = (short)(u & 0xffff);
                aqH[f][j] = (short)(u >> 16);
            }
        }
    }

    f32x4 oL[16], oH[16];
#pragma unroll
    for (int t = 0; t < 16; t++) {
        oL[t] = (f32x4){0.f, 0.f, 0.f, 0.f};
        oH[t] = (f32x4){0.f, 0.f, 0.f, 0.f};
    }
    float m_w = -__builtin_inff();
    float l_pL = 0.f, l_pH = 0.f;        // partial l for query l16 (+16 for H)

    // stage both key-halves' K/V tiles (block-wide)
    auto stage = [&](int buf, int m0) {
        unsigned short* dst = &KV[buf][0];
#pragma unroll
        for (int p = 0; p < 4; p++) {               // K: 2048 chunks
            int chunk = p * 512 + tid;
            int half = chunk >> 10;
            int idx  = chunk & 1023;
            int key = idx >> 5;
            int j = (idx & 31) ^ (key & 31);
            load_lds16(kb + (size_t)(half * 2048 + m0 + key) * C + j * 8,
                       dst + half * 16384 + idx * 8);
        }
#pragma unroll
        for (int p = 0; p < 4; p++) {               // V: 2048 chunks
            int chunk = p * 512 + tid;
            int half = chunk >> 10;
            int idx  = chunk & 1023;
            int c = idx >> 2;
            int s = idx & 3;
            int j = (s - (c >> 1)) & 3;             // source pre-rotation
            load_lds16(vcb + (size_t)c * N + half * 2048 + m0 + j * 8,
                       dst + half * 16384 + 8192 + idx * 8);
        }
    };

    // S^T tile registers (persist across the pipeline boundary)
    f32x4 tL0, tL1, tH0, tH1;

    // QK cluster: S^T = K Q^T for tile in KV[buf]
    auto qk = [&](int buf) {
        const unsigned short* Kb = &KV[buf][ks * 16384];
        f32x4 a0 = {0.f,0.f,0.f,0.f}, a1 = {0.f,0.f,0.f,0.f};
        f32x4 b0 = {0.f,0.f,0.f,0.f}, b1 = {0.f,0.f,0.f,0.f};
#pragma unroll
        for (int f = 0; f < 8; f++) {
            const int j = f * 4 + quad;
            int k0 = l16, k1 = 16 + l16;
            short8 kf0 = *(const short8*)(Kb + (k0 * 32 + (j ^ (k0 & 31))) * 8);
            short8 kf1 = *(const short8*)(Kb + (k1 * 32 + (j ^ (k1 & 31))) * 8);
            a0 = MFMA16(kf0, aqL[f], a0);
            a1 = MFMA16(kf1, aqL[f], a1);
            b0 = MFMA16(kf0, aqH[f], b0);
            b1 = MFMA16(kf1, aqH[f], b1);
        }
        tL0 = a0; tL1 = a1; tH0 = b0; tH1 = b1;
    };

    const int vsl = ((quad + (l16 >> 1)) & 3) * 8;  // V read slot (lane-const)

    stage(0, 0);
    __syncthreads();            // stage(0) landed
    stage(1, 32);               // in flight through qk(0)+softmax(0)+PV... 
    qk(0);

    for (int it = 0; it < 64; ++it) {
        // ---- softmax(it): wave-wide online max (base-2; VALU-only)
        float mx = fmaxf(fmaxf(fmaxf(tL0[0], tL0[1]), fmaxf(tL0[2], tL0[3])),
                         fmaxf(fmaxf(tL1[0], tL1[1]), fmaxf(tL1[2], tL1[3])));
        mx = fmaxf(mx, fmaxf(fmaxf(fmaxf(tH0[0], tH0[1]), fmaxf(tH0[2], tH0[3])),
                             fmaxf(fmaxf(tH1[0], tH1[1]), fmaxf(tH1[2], tH1[3]))));
        mx = rowmax16_dpp(mx);
        mx = wavemax_bcast(mx);

        // defer-rescale (T13): only pay the rescale when max grows by >8
        if (mx > m_w + 8.0f) {
            const float al = exp2f(m_w - mx);   // 0 on first iter
            m_w = mx;
            l_pL *= al; l_pH *= al;
#pragma unroll
            for (int t = 0; t < 16; t++) { oL[t] *= al; oH[t] *= al; }
        }
        const float mn = m_w;

        // exps -> lane-local PV A-fragments (zero LDS)
        uint4v apLu, apHu;
#pragma unroll
        for (int w = 0; w < 4; w++) {
            float e0 = exp2f(tL0[w] - mn);
            float e1 = exp2f(tL1[w] - mn);
            l_pL += e0 + e1;
            union { __hip_bfloat162 v; unsigned int u; } cv;
            cv.v = __float22bfloat162_rn(float2{e0, e1});
            apLu[w] = cv.u;
            float g0 = exp2f(tH0[w] - mn);
            float g1 = exp2f(tH1[w] - mn);
            l_pH += g0 + g1;
            union { __hip_bfloat162 v; unsigned int u; } cw;
            cw.v = __float22bfloat162_rn(float2{g0, g1});
            apHu[w] = cw.u;
        }
        short8 apL, apH;
        {
            union { uint4v u; short8 s; } c1; c1.u = apLu; apL = c1.s;
            union { uint4v u; short8 s; } c2; c2.u = apHu; apH = c2.s;
        }

        // ---- PV(it): 16 channel-tiles from KV[it&1] (staged long ago)
        {
            const unsigned short* Vb = &KV[it & 1][ks * 16384 + 8192];
#pragma unroll
            for (int t = 0; t < 16; t++) {
                short8 vf = *(const short8*)(Vb + t * 512 + l16 * 32 + vsl);
                oL[t] = MFMA16(apL, vf, oL[t]);
                oH[t] = MFMA16(apH, vf, oH[t]);
            }
        }

        // ---- single barrier: (a) stage(it+1) landed -> qk(it+1) safe;
        //      (b) PV(it) reads of KV[it&1] done -> stage(it+2) may overwrite.
        if (it < 63) {
            __syncthreads();
            if (it < 62) stage(it & 1, (it + 2) * 32);   // buf it&1, loads fly
            qk((it + 1) & 1);                            // reads buf (it+1)&1
        }
    }

    // ---- reduce l partials across quads (keys split over the 4 quad-lanes)
    l_pL += __shfl_xor(l_pL, 16);
    l_pL += __shfl_xor(l_pL, 32);
    l_pH += __shfl_xor(l_pH, 16);
    l_pH += __shfl_xor(l_pH, 32);
    if (quad == 0) {
        Lw[wave][l16] = l_pL;
        Lw[wave][16 + l16] = l_pH;
    }

    // ---- in-block merge of the two key-halves
    float* CombF = (float*)(&KV[0][0]);   // 4 waves x 32 q x 256 c f32 = 128 KB
    __syncthreads();                       // loop reads done + Lw visible
    if (ks == 1) {
#pragma unroll
        for (int t = 0; t < 16; t++) {
#pragma unroll
            for (int r = 0; r < 4; r++) {
                CombF[(size_t)(w4 * 32 + quad * 4 + r) * 256 + t * 16 + l16] = oL[t][r];
                CombF[(size_t)(w4 * 32 + 16 + quad * 4 + r) * 256 + t * 16 + l16] = oH[t][r];
            }
        }
        if (lane == 0) MwL[w4] = m_w;
    }
    __syncthreads();
    if (ks == 0) {
        const float g = gamma[0];
        const float m2w = MwL[w4];
        const float mt = fmaxf(m_w, m2w);
        const float f1 = exp2f(m_w - mt);
        const float f2 = exp2f(m2w - mt);
        float linv[2][4];
#pragma unroll
        for (int h = 0; h < 2; h++)
#pragma unroll
            for (int r = 0; r < 4; r++) {
                const int q = h * 16 + quad * 4 + r;
                linv[h][r] = g / (Lw[w4][q] * f1 + Lw[4 + w4][q] * f2);
            }
#pragma unroll
        for (int t = 0; t < 16; t++) {
            const int c = t * 16 + l16;
#pragma unroll
            for (int h = 0; h < 2; h++) {
                const int nb = q0 + h * 16 + quad * 4;
                f32x4 o1 = h ? oH[t] : oL[t];
                f32x4 ov;
#pragma unroll
                for (int r = 0; r < 4; r++) {
                    float o2 = CombF[(size_t)(w4 * 32 + h * 16 + quad * 4 + r) * 256 + c];
                    ov[r] = (o1[r] * f1 + o2 * f2) * linv[h][r];
                }
                size_t idx = ((size_t)(b * C + c)) * N + nb;
                f32x4 xv = *(const f32x4*)(x + idx);
                *(f32x4*)(out + idx) = ov + xv;
            }
        }
    }
}

extern "C" void kernel_launch(void* const* d_in, const int* in_sizes, int n_in,
                              void* d_out, int out_size, void* d_ws, size_t ws_size,
                              hipStream_t stream) {
    const int B = 8, C = 256, N = 4096;
    const float* x     = (const float*)d_in[0];
    const float* wq    = (const float*)d_in[1];
    const float* bq    = (const float*)d_in[2];
    const float* wk    = (const float*)d_in[3];
    const float* bk    = (const float*)d_in[4];
    const float* wv    = (const float*)d_in[5];
    const float* bv    = (const float*)d_in[6];
    const float* gamma = (const float*)d_in[7];
    float* out = (float*)d_out;

    unsigned short* Qc = (unsigned short*)d_ws;             // [B][C][N] bf16 (x log2e), pair-interleaved
    unsigned short* Kr = Qc + (size_t)B * C * N;            // [B][N][C] bf16
    unsigned short* Vc = Kr + (size_t)B * N * C;            // [B][C][N] bf16, pair-interleaved
    unsigned short* Wb = Vc + (size_t)B * C * N;            // [3][256][256] bf16

    wcvt_kernel<<<dim3(192), 256, 0, stream>>>(wq, wk, wv, Wb);
    qkv_kernel<<<dim3(1024), 256, 0, stream>>>(x, Wb, bq, bk, bv, Qc, Kr, Vc);
    attn_kernel<<<dim3(256), 512, 0, stream>>>(Qc, Kr, Vc, x, gamma, out);
}